// Round 5
// baseline (207.033 us; speedup 1.0000x reference)
//
#include <hip/hip_runtime.h>
#include <hip/hip_bf16.h>
#include <cstdint>
#include <cfloat>

#define NTOK 16384
#define DIN  1024
#define DOUT 1024
#define NEXP 8
#define RLORA 16
#define KTOT 1152          // DIN + NEXP*RLORA
#define SCALE_LORA 2.0f    // alpha/rank = 32/16

typedef __attribute__((ext_vector_type(8))) short bf16x8;
typedef __attribute__((ext_vector_type(4))) float f32x4;
typedef __attribute__((ext_vector_type(2))) unsigned int u32x2;

__device__ __forceinline__ unsigned short f2bf(float f) {
  __hip_bfloat16 h = __float2bfloat16(f);
  unsigned short u;
  __builtin_memcpy(&u, &h, 2);
  return u;
}

__device__ __forceinline__ void gld_lds16(const void* g, void* l) {
  __builtin_amdgcn_global_load_lds((const __attribute__((address_space(1))) void*)g,
                                   (__attribute__((address_space(3))) void*)l,
                                   16, 0, 0);
}

// ---------------------------------------------------------------------------
// Transpose Wcat = [W_base; Bcat]^T -> WcatT [1024][1152] bf16, LDS-tiled.
// ---------------------------------------------------------------------------
__global__ __launch_bounds__(256) void k_transW(const float* __restrict__ Wb,
                                                const float* __restrict__ B,
                                                unsigned short* __restrict__ WcatT) {
  __shared__ unsigned short T[64][66];
  const int k0 = blockIdx.x * 64, j0 = blockIdx.y * 64;
  const int t = threadIdx.x;
#pragma unroll
  for (int p = 0; p < 4; ++p) {
    int kk = p * 16 + (t >> 4);
    int c4 = (t & 15) * 4;
    int k = k0 + kk;
    const float* src = (k < 1024) ? (Wb + (size_t)k * 1024) : (B + (size_t)(k - 1024) * 1024);
    float4 v = *(const float4*)(src + j0 + c4);
    T[kk][c4 + 0] = f2bf(v.x); T[kk][c4 + 1] = f2bf(v.y);
    T[kk][c4 + 2] = f2bf(v.z); T[kk][c4 + 3] = f2bf(v.w);
  }
  __syncthreads();
#pragma unroll
  for (int p = 0; p < 2; ++p) {
    int jj = p * 32 + (t >> 3);
    int kc = (t & 7) * 8;
    unsigned short buf[8];
#pragma unroll
    for (int i = 0; i < 8; ++i) buf[i] = T[kc + i][jj];
    uint4 u; __builtin_memcpy(&u, buf, 16);
    *(uint4*)(WcatT + (size_t)(j0 + jj) * KTOT + k0 + kc) = u;
  }
}

// ---------------------------------------------------------------------------
// AcatT[e*16+r][d] = A[e][d][r] bf16, LDS-tiled. grid (4, 8): (d-chunk, e).
// ---------------------------------------------------------------------------
__global__ __launch_bounds__(256) void k_transA(const float* __restrict__ A,
                                                unsigned short* __restrict__ AcatT) {
  __shared__ unsigned short T[256][17];
  const int e = blockIdx.y, d0 = blockIdx.x * 256;
  const int t = threadIdx.x;
#pragma unroll
  for (int p = 0; p < 4; ++p) {
    int idx = p * 256 + t;
    int d = idx >> 2;
    int rr = (idx & 3) * 4;
    float4 v = *(const float4*)(A + (size_t)e * 16384 + (size_t)(d0 + d) * 16 + rr);
    T[d][rr + 0] = f2bf(v.x); T[d][rr + 1] = f2bf(v.y);
    T[d][rr + 2] = f2bf(v.z); T[d][rr + 3] = f2bf(v.w);
  }
  __syncthreads();
#pragma unroll
  for (int p = 0; p < 2; ++p) {
    int slot = p * 256 + t;
    int r = slot >> 5;
    int dc = (slot & 31) * 8;
    unsigned short buf[8];
#pragma unroll
    for (int i = 0; i < 8; ++i) buf[i] = T[dc + i][r];
    uint4 u; __builtin_memcpy(&u, buf, 16);
    *(uint4*)(AcatT + (size_t)(e * 16 + r) * 1024 + d0 + dc) = u;
  }
}

// ---------------------------------------------------------------------------
// WgT[e][d] = Wg[d][e] fp32 (32 KB). grid(4), block(256).
// ---------------------------------------------------------------------------
__global__ __launch_bounds__(256) void k_transG(const float* __restrict__ Wg,
                                                float* __restrict__ WgT) {
  int d = blockIdx.x * 256 + threadIdx.x;
  float4 a = *(const float4*)(Wg + (size_t)d * 8);
  float4 b = *(const float4*)(Wg + (size_t)d * 8 + 4);
  WgT[0 * 1024 + d] = a.x; WgT[1 * 1024 + d] = a.y;
  WgT[2 * 1024 + d] = a.z; WgT[3 * 1024 + d] = a.w;
  WgT[4 * 1024 + d] = b.x; WgT[5 * 1024 + d] = b.y;
  WgT[6 * 1024 + d] = b.z; WgT[7 * 1024 + d] = b.w;
}

// ---------------------------------------------------------------------------
// Router v5: 16 lanes per token, 4 tokens per wave, 16 tokens per block.
// 16 independent upfront token loads (high MLP), 4-step butterfly (16 lanes),
// nontemporal token/Xcat traffic to keep L1 for WgT. grid 1024.
// ---------------------------------------------------------------------------
__global__ __launch_bounds__(256) void k_router(const float* __restrict__ tokens,
                                                const float* __restrict__ WgT,
                                                float* __restrict__ out_logits,
                                                float* __restrict__ out_sel,
                                                float* __restrict__ out_w,
                                                unsigned short* __restrict__ Xcat,
                                                float4* __restrict__ gateinfo) {
  const int wid = threadIdx.x >> 6;
  const int lane = threadIdx.x & 63;
  const int g = lane >> 4;          // token group within wave
  const int il = lane & 15;         // lane within token
  const int t = (blockIdx.x * 4 + wid) * 4 + g;

  const float* xrow = tokens + (size_t)t * DIN;

  // 16 independent float4 loads covering the whole row (16 lanes x 4 x 16 j)
  f32x4 xv[16];
#pragma unroll
  for (int j = 0; j < 16; ++j)
    xv[j] = __builtin_nontemporal_load((const f32x4*)(xrow + j * 64 + il * 4));

  // bf16 convert + nontemporal store to Xcat cols [0,1024)
  unsigned short* xb = Xcat + (size_t)t * KTOT;
#pragma unroll
  for (int j = 0; j < 16; ++j) {
    unsigned short hb[4];
    hb[0] = f2bf(xv[j][0]); hb[1] = f2bf(xv[j][1]);
    hb[2] = f2bf(xv[j][2]); hb[3] = f2bf(xv[j][3]);
    u32x2 u;
    __builtin_memcpy(&u, hb, 8);
    __builtin_nontemporal_store(u, (u32x2*)(xb + j * 64 + il * 4));
  }

  // fp32 logits: 8 expert accumulators, WgT [e][d] reads 256 B coalesced
  // per 16-lane group (broadcast across the 4 groups).
  float acc[8] = {0, 0, 0, 0, 0, 0, 0, 0};
#pragma unroll
  for (int j = 0; j < 16; ++j) {
#pragma unroll
    for (int e = 0; e < 8; ++e) {
      f32x4 w = *(const f32x4*)(WgT + (size_t)e * 1024 + j * 64 + il * 4);
      acc[e] = fmaf(xv[j][0], w[0], fmaf(xv[j][1], w[1],
               fmaf(xv[j][2], w[2], fmaf(xv[j][3], w[3], acc[e]))));
    }
  }
  // 4-step butterfly within the 16-lane group
#pragma unroll
  for (int s = 1; s < 16; s <<= 1) {
#pragma unroll
    for (int e = 0; e < 8; ++e) acc[e] += __shfl_xor(acc[e], s, 64);
  }

  // top-2 (strict > keeps lowest index on ties, matching jax top_k)
  float v0 = -FLT_MAX, v1 = -FLT_MAX;
  int i0 = -1, i1 = -1;
#pragma unroll
  for (int e = 0; e < 8; ++e) {
    float v = acc[e];
    if (v > v0) { v1 = v0; i1 = i0; v0 = v; i0 = e; }
    else if (v > v1) { v1 = v; i1 = e; }
  }
  float ex = expf(v1 - v0);
  float inv = 1.0f / (1.0f + ex);
  float w0 = inv, w1 = ex * inv;

  if (il == 0) {
    float4* lg = (float4*)(out_logits + (size_t)t * 8);
    lg[0] = make_float4(acc[0], acc[1], acc[2], acc[3]);
    lg[1] = make_float4(acc[4], acc[5], acc[6], acc[7]);
    *(float2*)(out_sel + (size_t)t * 2) = make_float2((float)i0, (float)i1);
    *(float2*)(out_w + (size_t)t * 2) = make_float2(w0, w1);
    gateinfo[t] = make_float4((float)i0, (float)i1, w0 * SCALE_LORA, w1 * SCALE_LORA);
  }
}

// ---------------------------------------------------------------------------
// H-GEMM + gating. BM=64, BN=64, BK=256 (4 K-steps: latency-chain minimized),
// 64 KB LDS, 2 blocks/CU, grid 512. 16 staged loads/thread in flight per step.
// ---------------------------------------------------------------------------
__global__ __launch_bounds__(256) void k_hgemm(const unsigned short* __restrict__ Xg,
                                               const unsigned short* __restrict__ Ag,
                                               const float4* __restrict__ gateinfo,
                                               unsigned short* __restrict__ Xout) {
  constexpr int BK = 256;
  __shared__ alignas(16) unsigned short As[64 * BK];  // 32 KB
  __shared__ alignas(16) unsigned short Bs[64 * BK];  // 32 KB
  const int tid = threadIdx.x;
  const int lane = tid & 63;
  const int wid = tid >> 6;
  const int id = blockIdx.x;
  const int xcd = id & 7, s5 = id >> 3;
  const int n0 = (s5 & 1) * 64;
  const int m0 = (xcd * 32 + (s5 >> 1)) * 64;
  const int wm = (wid >> 1) * 32, wn = (wid & 1) * 32;
  const int quad = lane >> 4, r16 = lane & 15;

  f32x4 acc[2][2] = {};

  for (int k0 = 0; k0 < 1024; k0 += BK) {
#pragma unroll
    for (int i = 0; i < 8; ++i) {          // A: 64 rows x 32 chunks = 2048
      int s = i * 256 + tid;
      int r = s >> 5, c = s & 31;
      int q = c ^ ((r >> 1) & 31);
      gld_lds16(Xg + (size_t)(m0 + r) * KTOT + k0 + q * 8, (char*)As + s * 16);
    }
#pragma unroll
    for (int i = 0; i < 8; ++i) {          // B: 64 rows x 32 chunks
      int s = i * 256 + tid;
      int r = s >> 5, c = s & 31;
      int q = c ^ ((r >> 1) & 31);
      gld_lds16(Ag + (size_t)(n0 + r) * 1024 + k0 + q * 8, (char*)Bs + s * 16);
    }
    __syncthreads();

#pragma unroll
    for (int h = 0; h < 8; ++h) {
      bf16x8 af[2], bfr[2];
#pragma unroll
      for (int mi = 0; mi < 2; ++mi) {
        int m = wm + mi * 16 + r16;
        int slot = m * 32 + ((h * 4 + quad) ^ ((m >> 1) & 31));
        af[mi] = *(const bf16x8*)((const char*)As + slot * 16);
      }
#pragma unroll
      for (int ni = 0; ni < 2; ++ni) {
        int n = wn + ni * 16 + r16;
        int slot = n * 32 + ((h * 4 + quad) ^ ((n >> 1) & 31));
        bfr[ni] = *(const bf16x8*)((const char*)Bs + slot * 16);
      }
#pragma unroll
      for (int mi = 0; mi < 2; ++mi)
#pragma unroll
        for (int ni = 0; ni < 2; ++ni)
          acc[mi][ni] = __builtin_amdgcn_mfma_f32_16x16x32_bf16(af[mi], bfr[ni], acc[mi][ni], 0, 0, 0);
    }
    __syncthreads();
  }

#pragma unroll
  for (int mi = 0; mi < 2; ++mi)
#pragma unroll
    for (int r = 0; r < 4; ++r) {
      int row = m0 + wm + mi * 16 + quad * 4 + r;
      float4 gi = gateinfo[row];
      int ie0 = (int)gi.x, ie1 = (int)gi.y;
#pragma unroll
      for (int ni = 0; ni < 2; ++ni) {
        int c = n0 + wn + ni * 16 + r16;
        int e = c >> 4;
        float h = acc[mi][ni][r];
        float v = (e == ie0) ? gi.z * h : ((e == ie1) ? gi.w * h : 0.f);
        Xout[(size_t)row * KTOT + 1024 + c] = f2bf(v);
      }
    }
}

// ---------------------------------------------------------------------------
// Main GEMM: out = Xcat @ WcatT^T. BM=BN=128, BK=64 (h-loop), 4 waves 64x64.
// ---------------------------------------------------------------------------
__global__ __launch_bounds__(256) void k_gemm_main(const unsigned short* __restrict__ Xg,
                                                   const unsigned short* __restrict__ Wg,
                                                   float* __restrict__ C) {
  constexpr int BK = 64;
  __shared__ alignas(16) unsigned short As[128 * BK];  // 16 KB
  __shared__ alignas(16) unsigned short Bs[128 * BK];  // 16 KB
  const int tid = threadIdx.x;
  const int lane = tid & 63;
  const int wid = tid >> 6;
  const int id = blockIdx.x;
  const int xcd = id & 7, s5 = id >> 3;
  const int n0 = (s5 & 7) * 128;
  const int m0 = (xcd * 16 + (s5 >> 3)) * 128;
  const int wm = (wid >> 1) * 64, wn = (wid & 1) * 64;
  const int quad = lane >> 4, r16 = lane & 15;

  f32x4 acc[4][4] = {};

  for (int k0 = 0; k0 < KTOT; k0 += BK) {
#pragma unroll
    for (int i = 0; i < 4; ++i) {          // A: 128 rows x 8 chunks = 1024
      int s = i * 256 + tid;
      int r = s >> 3, c = s & 7;
      int q = c ^ ((r >> 1) & 7);
      gld_lds16(Xg + (size_t)(m0 + r) * KTOT + k0 + q * 8, (char*)As + s * 16);
    }
#pragma unroll
    for (int i = 0; i < 4; ++i) {
      int s = i * 256 + tid;
      int r = s >> 3, c = s & 7;
      int q = c ^ ((r >> 1) & 7);
      gld_lds16(Wg + (size_t)(n0 + r) * KTOT + k0 + q * 8, (char*)Bs + s * 16);
    }
    __syncthreads();

#pragma unroll
    for (int h = 0; h < 2; ++h) {
      bf16x8 af[4], bfr[4];
#pragma unroll
      for (int mi = 0; mi < 4; ++mi) {
        int m = wm + mi * 16 + r16;
        int slot = m * 8 + ((h * 4 + quad) ^ ((m >> 1) & 7));
        af[mi] = *(const bf16x8*)((const char*)As + slot * 16);
      }
#pragma unroll
      for (int ni = 0; ni < 4; ++ni) {
        int n = wn + ni * 16 + r16;
        int slot = n * 8 + ((h * 4 + quad) ^ ((n >> 1) & 7));
        bfr[ni] = *(const bf16x8*)((const char*)Bs + slot * 16);
      }
#pragma unroll
      for (int mi = 0; mi < 4; ++mi)
#pragma unroll
        for (int ni = 0; ni < 4; ++ni)
          acc[mi][ni] = __builtin_amdgcn_mfma_f32_16x16x32_bf16(af[mi], bfr[ni], acc[mi][ni], 0, 0, 0);
    }
    __syncthreads();
  }

  // C/D layout: col = lane&15, row = quad*4 + reg  [m89/m91]
#pragma unroll
  for (int mi = 0; mi < 4; ++mi)
#pragma unroll
    for (int ni = 0; ni < 4; ++ni)
#pragma unroll
      for (int r = 0; r < 4; ++r) {
        int row = m0 + wm + mi * 16 + quad * 4 + r;
        int cc = n0 + wn + ni * 16 + r16;
        C[(size_t)row * 1024 + cc] = acc[mi][ni][r];
      }
}

// ---------------------------------------------------------------------------
extern "C" void kernel_launch(void* const* d_in, const int* in_sizes, int n_in,
                              void* d_out, int out_size, void* d_ws, size_t ws_size,
                              hipStream_t stream) {
  const float* tokens = (const float*)d_in[0];
  const float* Wb     = (const float*)d_in[1];
  const float* A      = (const float*)d_in[2];
  const float* B      = (const float*)d_in[3];
  const float* Wg     = (const float*)d_in[4];
  float* out = (float*)d_out;

  char* ws = (char*)d_ws;
  unsigned short* Xcat  = (unsigned short*)(ws);                 // [16384][1152] bf16  37748736 B
  unsigned short* WcatT = (unsigned short*)(ws + 37748736);      // [1024][1152] bf16    2359296 B
  unsigned short* AcatT = (unsigned short*)(ws + 40108032);      // [128][1024] bf16      262144 B
  float4*         ginfo = (float4*)(ws + 40370176);              // [16384] float4       262144 B
  float*          WgT   = (float*)(ws + 40632320);               // [8][1024] fp32         32768 B

  float* out_logits = out + (size_t)16384 * 1024;
  float* out_sel    = out_logits + (size_t)16384 * 8;
  float* out_w      = out_sel + (size_t)16384 * 2;

  k_transW<<<dim3(18, 16), dim3(256), 0, stream>>>(Wb, B, WcatT);
  k_transA<<<dim3(4, 8), dim3(256), 0, stream>>>(A, AcatT);
  k_transG<<<dim3(4), dim3(256), 0, stream>>>(Wg, WgT);
  k_router<<<dim3(1024), dim3(256), 0, stream>>>(tokens, WgT, out_logits, out_sel, out_w, Xcat, ginfo);
  k_hgemm<<<dim3(512), dim3(256), 0, stream>>>(Xcat, AcatT, ginfo, Xcat);
  k_gemm_main<<<dim3(1024), dim3(256), 0, stream>>>(Xcat, WcatT, out);
}